// Round 3
// baseline (300.778 us; speedup 1.0000x reference)
//
#include <hip/hip_runtime.h>

typedef unsigned short u16;
typedef u16   u16x8 __attribute__((ext_vector_type(8)));
typedef short s16x8 __attribute__((ext_vector_type(8)));
typedef float f32x4 __attribute__((ext_vector_type(4)));

__device__ __forceinline__ float b2f(u16 u) {
    return __uint_as_float(((unsigned)u) << 16);
}
__device__ __forceinline__ u16 f2b(float f) {
    unsigned x = __float_as_uint(f);
    x += 0x7fffu + ((x >> 16) & 1u);
    return (u16)(x >> 16);
}
// async global->LDS, 16B per lane; LDS dest = wave-uniform base + lane*16
__device__ __forceinline__ void gload_lds(const u16* g, u16* l) {
    __builtin_amdgcn_global_load_lds(
        (const __attribute__((address_space(1))) unsigned int*)g,
        (__attribute__((address_space(3))) unsigned int*)l, 16, 0, 0);
}

#define THETA_SCALE 0.05190512648261f   // log2(10000)/256

// ---------------- prep: Xb = bf16(x) + WT = bf16(Wqk^T) + zero kvbuf/ksum ---
__global__ __launch_bounds__(256)
void k_prep(const float* __restrict__ X, u16* __restrict__ Xb,
            const float* __restrict__ W, u16* __restrict__ WT,
            float* __restrict__ kvz) {
    if (blockIdx.x < 4096) {
        size_t i = (size_t)(blockIdx.x * 256 + threadIdx.x) * 8;
        float4 a = *(const float4*)(X + i);
        float4 b = *(const float4*)(X + i + 4);
        u16x8 r;
        r[0] = f2b(a.x); r[1] = f2b(a.y); r[2] = f2b(a.z); r[3] = f2b(a.w);
        r[4] = f2b(b.x); r[5] = f2b(b.y); r[6] = f2b(b.z); r[7] = f2b(b.w);
        *(u16x8*)(Xb + i) = r;
    } else if (blockIdx.x < 4608) {
        __shared__ float tile[32][33];
        int bid = blockIdx.x - 4096;        // 0..511 = 32 x 16
        int c0 = (bid & 31) * 32;
        int r0 = (bid >> 5) * 32;
        int tx = threadIdx.x & 31;
        int ty = threadIdx.x >> 5;
        #pragma unroll
        for (int i = 0; i < 4; ++i) {
            int r = ty + i * 8;
            tile[r][tx] = W[(size_t)(r0 + r) * 1024 + c0 + tx];
        }
        __syncthreads();
        #pragma unroll
        for (int i = 0; i < 4; ++i) {
            int r = ty + i * 8;
            WT[(size_t)(c0 + r) * 512 + r0 + tx] = f2b(tile[tx][r]);
        }
    } else {
        // zero kvbuf (65536 f) + ksum (2048 f): 66 blocks x 1024 floats
        size_t i = (size_t)(blockIdx.x - 4608) * 1024 + threadIdx.x * 4;
        *(float4*)(kvz + i) = make_float4(0.f, 0.f, 0.f, 0.f);
    }
}

// ---------------- GEMM + fused kv: Xb x WT + bias, elu+1 --------------------
// 256x256 tile, 8 waves (2M x 4N), BK=64 double-buffered, counted vmcnt(8).
// Q-blocks (n0<512): write Qb. K-blocks (n0>=512): STREAM each acc element
// (AGPR) -> elu+1 -> ksum -> rope (scalar shfl) -> bf16 -> krT LDS, no
// write-back (keeps acc in AGPRs, no spills). Then kv = kr^T @ v via MFMA
// in two 4-head passes reusing the gemm LDS; atomicAdd kvbuf/ksum handoff.
__global__ __launch_bounds__(512, 2)
void k_gemm(const u16* __restrict__ Xb, const u16* __restrict__ WT,
            const float* __restrict__ bqk,
            u16* __restrict__ Qb,
            float* __restrict__ kvbuf, float* __restrict__ ksum) {
    __shared__ u16 SM[67584];            // 132 KB: gemm As|Bs / kv krT|vT
    const int t = threadIdx.x;           // 0..511
    const int m0 = blockIdx.x * 256;
    const int n0 = blockIdx.y * 256;
    const int lane = t & 63;
    const int wave = t >> 6;             // 0..7
    const int wm = (wave >> 2) * 128;    // 2 m-wave rows
    const int wn = (wave & 3) * 64;      // 4 n-wave cols
    const int quad = lane >> 4;
    const int l16 = lane & 15;
    const int srow = lane >> 3;          // staging: row within wave's 8-row slice
    const int skc  = lane & 7;           // staging: 16B granule within row

    u16* As0 = SM;                       // [2][256*64]
    u16* Bs0 = SM + 32768;               // [2][256*64]

    f32x4 acc[8][4];
    #pragma unroll
    for (int i = 0; i < 8; ++i)
        #pragma unroll
        for (int j = 0; j < 4; ++j) acc[i][j] = (f32x4){0.f, 0.f, 0.f, 0.f};

    // prologue: stage K-tile 0 into buffer 0 (8 gloads/wave)
    #pragma unroll
    for (int c = 0; c < 4; ++c) {
        int row = c * 64 + wave * 8 + srow;
        int kcs = (skc ^ (row & 7)) * 8;
        gload_lds(Xb + (size_t)(m0 + row) * 512 + kcs,
                  As0 + (c * 64 + wave * 8) * 64);
        gload_lds(WT + (size_t)(n0 + row) * 512 + kcs,
                  Bs0 + (c * 64 + wave * 8) * 64);
    }

    for (int kt = 0; kt < 8; ++kt) {
        const int cur = kt & 1;
        if (kt < 7) {
            const int k0 = (kt + 1) * 64;
            #pragma unroll
            for (int c = 0; c < 4; ++c) {
                int row = c * 64 + wave * 8 + srow;
                int kcs = (skc ^ (row & 7)) * 8;
                gload_lds(Xb + (size_t)(m0 + row) * 512 + k0 + kcs,
                          As0 + (cur ^ 1) * 16384 + (c * 64 + wave * 8) * 64);
                gload_lds(WT + (size_t)(n0 + row) * 512 + k0 + kcs,
                          Bs0 + (cur ^ 1) * 16384 + (c * 64 + wave * 8) * 64);
            }
            // wait for this tile's 8 loads; next tile's 8 stay in flight
            asm volatile("s_waitcnt vmcnt(8)" ::: "memory");
        } else {
            asm volatile("s_waitcnt vmcnt(0)" ::: "memory");
        }
        __builtin_amdgcn_s_barrier();
        asm volatile("" ::: "memory");

        #pragma unroll
        for (int s = 0; s < 2; ++s) {
            const int cb = s * 4 + quad;
            s16x8 af[8], bf[4];
            #pragma unroll
            for (int f = 0; f < 8; ++f) {
                int row = wm + f * 16 + l16;
                af[f] = *(const s16x8*)&As0[cur * 16384 + row * 64 +
                                            ((cb ^ (row & 7)) * 8)];
            }
            #pragma unroll
            for (int j = 0; j < 4; ++j) {
                int row = wn + j * 16 + l16;
                bf[j] = *(const s16x8*)&Bs0[cur * 16384 + row * 64 +
                                            ((cb ^ (row & 7)) * 8)];
            }
            __builtin_amdgcn_s_setprio(1);
            #pragma unroll
            for (int f = 0; f < 8; ++f)
                #pragma unroll
                for (int j = 0; j < 4; ++j)
                    acc[f][j] = __builtin_amdgcn_mfma_f32_16x16x32_bf16(
                        af[f], bf[j], acc[f][j], 0, 0, 0);
            __builtin_amdgcn_s_setprio(0);
        }
        asm volatile("" ::: "memory");
        __builtin_amdgcn_s_barrier();
    }

    if (n0 < 512) {
        // ---- Q epilogue: bias + elu+1 -> Qb (bf16) ----
        #pragma unroll
        for (int f = 0; f < 8; ++f)
            #pragma unroll
            for (int j = 0; j < 4; ++j) {
                int col = n0 + wn + j * 16 + l16;
                float bias = bqk[col];
                #pragma unroll
                for (int r = 0; r < 4; ++r) {
                    int grow = m0 + wm + f * 16 + quad * 4 + r;
                    float v = acc[f][j][r] + bias;
                    v = v > 0.f ? v + 1.f : __expf(v);   // elu(v)+1
                    Qb[(size_t)grow * 512 + (col & 511)] = f2b(v);
                }
            }
        return;
    }

    // ---- K path: stream acc -> krT LDS; kv via MFMA over two 4-head passes
    const int b = m0 >> 12;
    u16* krTb = SM;             // [128][264] bf16, bank-rotated cols
    u16* vTb  = SM + 33792;     // [128][264] bf16
    const int mypass = wn >> 7;          // wave's kr data belongs to this pass
    float ksp[4] = {0.f, 0.f, 0.f, 0.f};

    for (int p = 0; p < 2; ++p) {
        if (p) __syncthreads();          // pass-0 frag reads done
        if (mypass == p) {
            // stream-convert this wave's acc into krTb (no write-back)
            #pragma unroll
            for (int j = 0; j < 4; ++j) {
                int colg = n0 + wn + j * 16 + l16;
                float bias = bqk[colg];
                int chL = (wn & 127) + j * 16 + l16;
                int rot = 16 * ((chL >> 3) & 3);
                int pairIdx = (colg - 512) >> 1;
                float th = exp2f(-THETA_SCALE * (float)pairIdx);
                float s16v, c16v;
                sincosf(16.f * th, &s16v, &c16v);
                float cr[4], sr[4];
                int nb0 = (m0 & 4095) + wm + quad * 4;
                #pragma unroll
                for (int r = 0; r < 4; ++r)
                    sincosf((float)(nb0 + r) * th, &sr[r], &cr[r]);
                #pragma unroll
                for (int f = 0; f < 8; ++f) {
                    #pragma unroll
                    for (int r = 0; r < 4; ++r) {
                        float v = acc[f][j][r] + bias;
                        float kf = v > 0.f ? v + 1.f : __expf(v);
                        ksp[j] += kf;
                        float kp = __shfl_xor(kf, 1);
                        float c = cr[r], s = sr[r];
                        float krv = (l16 & 1) ? (kp * s + kf * c)
                                              : (kf * c - kp * s);
                        int nloc = wm + f * 16 + quad * 4 + r;
                        krTb[chL * 264 + ((nloc + rot) & 255)] = f2b(krv);
                    }
                    #pragma unroll
                    for (int r = 0; r < 4; ++r) {   // advance angle by 16*th
                        float c = cr[r], s = sr[r];
                        cr[r] = c * c16v - s * s16v;
                        sr[r] = s * c16v + c * s16v;
                    }
                }
            }
        }
        // stage vT (transpose of Xb rows, L2-warm)
        #pragma unroll
        for (int cg = 0; cg < 4; ++cg)
            #pragma unroll
            for (int nh = 0; nh < 2; ++nh) {
                int nloc = nh * 128 + (t >> 2);
                int ch8 = cg * 32 + (t & 3) * 8;
                int chg = (n0 - 512) + p * 128 + ch8;
                u16x8 v8 = *(const u16x8*)(Xb +
                            (size_t)(m0 + nloc) * 512 + chg);
                #pragma unroll
                for (int jj = 0; jj < 8; ++jj) {
                    int chL = ch8 + jj;
                    int rot = 16 * ((chL >> 3) & 3);
                    vTb[chL * 264 + ((nloc + rot) & 255)] = v8[jj];
                }
            }
        __syncthreads();
        // compute: 16 tile-units (4 heads x 2x2), 2 per wave, K=256
        #pragma unroll
        for (int uu = 0; uu < 2; ++uu) {
            int u = wave + uu * 8;       // 0..15
            int hl = u >> 2;
            int dt = (u >> 1) & 1;
            int et = u & 1;
            int ca = hl * 32 + dt * 16 + l16;
            int cb = hl * 32 + et * 16 + l16;
            int ra = 16 * ((ca >> 3) & 3);
            int rb = 16 * ((cb >> 3) & 3);
            f32x4 a = {0.f, 0.f, 0.f, 0.f};
            #pragma unroll
            for (int ks = 0; ks < 8; ++ks) {
                s16x8 av = *(const s16x8*)&krTb[ca * 264 +
                            ((ks * 32 + quad * 8 + ra) & 255)];
                s16x8 bv = *(const s16x8*)&vTb[cb * 264 +
                            ((ks * 32 + quad * 8 + rb) & 255)];
                a = __builtin_amdgcn_mfma_f32_16x16x32_bf16(av, bv, a, 0, 0, 0);
            }
            int H = ((n0 - 512) >> 5) + p * 4 + hl;
            float* dst = kvbuf + (size_t)(b * 16 + H) * 1024;
            #pragma unroll
            for (int r = 0; r < 4; ++r)
                atomicAdd(&dst[(dt * 16 + quad * 4 + r) * 32 + et * 16 + l16],
                          a[r]);
        }
    }
    // ksum: reduce quad dim by shfl, one global atomic per col (quad==0 lanes)
    #pragma unroll
    for (int j = 0; j < 4; ++j) {
        float v = ksp[j];
        v += __shfl_xor(v, 16);
        v += __shfl_xor(v, 32);
        if (quad == 0)
            atomicAdd(&ksum[b * 512 + (n0 - 512) + wn + j * 16 + l16], v);
    }
}

// ---------------- out = z * (q_rope @ kv)/N + lepe (f32 to d_out) -----------
// phase 2 via MFMA: out[64x32] = qr[64x32] @ kv[32x32]; A = qr_s[row][d] bf16,
// B = kvT_s[e][d] bf16 (same [n][k] B-operand layout as the proven gemm);
// C round-trips LDS so the row-major lepe epilogue stays unchanged.
__global__ __launch_bounds__(256)
void k_out(const u16* __restrict__ Qb, const u16* __restrict__ Xb,
           const float* __restrict__ kvbuf, const float* __restrict__ ksum,
           const float* __restrict__ lw, const float* __restrict__ lb,
           float* __restrict__ OUT) {
    const int b = blockIdx.x >> 6;
    const int nb = (blockIdx.x & 63) * 64;
    const int hbase = blockIdx.y * 4;
    __shared__ u16 kvT_s[32 * 36];     // [e][d] bf16, stride 36
    __shared__ u16 qr_s[64 * 36];      // [row][d] bf16, stride 36
    __shared__ float out_s[64 * 36];   // [row][e] f32, stride 36
    __shared__ float ks_s[32];
    __shared__ float z_s[64];
    const int t = threadIdx.x;
    const int row = t >> 2;          // 0..63 local n
    const int c4 = t & 3;
    const int e0 = c4 * 8;
    const int lane = t & 63;
    const int wave = t >> 6;
    const int quad = lane >> 4;
    const int l16 = lane & 15;
    const float invN = 1.f / 4096.f;
    const int n = nb + row;
    const size_t rowbase = (size_t)(b * 4096 + n) * 512;

    for (int hh = 0; hh < 4; ++hh) {
        const int h = hbase + hh;
        const int bh = b * 16 + h;
        if (hh) __syncthreads();               // prev iteration LDS reads done
        // stage kvT (bf16, transposed) + kmean
        {
            int id = t * 4;                    // 0..1023, e varies fastest
            float4 kvv = *(const float4*)&kvbuf[(size_t)bh * 1024 + id];
            int d = id >> 5, e = id & 31;
            kvT_s[(e + 0) * 36 + d] = f2b(kvv.x * invN);
            kvT_s[(e + 1) * 36 + d] = f2b(kvv.y * invN);
            kvT_s[(e + 2) * 36 + d] = f2b(kvv.z * invN);
            kvT_s[(e + 3) * 36 + d] = f2b(kvv.w * invN);
        }
        if (t < 32) ks_s[t] = ksum[bh * 32 + t] * invN;
        __syncthreads();

        // phase 1: q (bf16), z partial dot, rope, stage qr bf16
        u16x8 q8 = *(const u16x8*)(Qb + rowbase + h * 32 + e0);
        float qf[8];
        #pragma unroll
        for (int j = 0; j < 8; ++j) qf[j] = b2f(q8[j]);
        float part = 0.f;
        #pragma unroll
        for (int j = 0; j < 8; ++j) part += qf[j] * ks_s[e0 + j];
        u16x8 qr8;
        #pragma unroll
        for (int p = 0; p < 4; ++p) {
            float th = exp2f(-THETA_SCALE * (float)(h * 16 + c4 * 4 + p));
            float sv, cv;
            sincosf((float)n * th, &sv, &cv);
            qr8[2 * p]     = f2b(qf[2 * p] * cv - qf[2 * p + 1] * sv);
            qr8[2 * p + 1] = f2b(qf[2 * p] * sv + qf[2 * p + 1] * cv);
        }
        *(u16x8*)&qr_s[row * 36 + e0] = qr8;
        part += __shfl_xor(part, 1);
        part += __shfl_xor(part, 2);
        if (c4 == 0) z_s[row] = 1.f / (part + 1e-6f);
        __syncthreads();

        // phase 2 (MFMA): wave = 16-row tile; 2 e-tiles; K=32 in one step
        {
            f32x4 zero4 = {0.f, 0.f, 0.f, 0.f};
            s16x8 a4 = *(const s16x8*)&qr_s[(wave * 16 + l16) * 36 + quad * 8];
            #pragma unroll
            for (int et = 0; et < 2; ++et) {
                s16x8 b4 = *(const s16x8*)&kvT_s[(et * 16 + l16) * 36 + quad * 8];
                f32x4 cacc = __builtin_amdgcn_mfma_f32_16x16x32_bf16(
                    a4, b4, zero4, 0, 0, 0);
                #pragma unroll
                for (int r = 0; r < 4; ++r)
                    out_s[(wave * 16 + quad * 4 + r) * 36 + et * 16 + l16] = cacc[r];
            }
        }
        __syncthreads();

        // epilogue: read out_s row-major, z scale + lepe + store f32
        const float z = z_s[row];
        float4 o0 = *(const float4*)&out_s[row * 36 + e0];
        float4 o1 = *(const float4*)&out_s[row * 36 + e0 + 4];
        float o[8] = {o0.x, o0.y, o0.z, o0.w, o1.x, o1.y, o1.z, o1.w};
        const int cb = h * 32 + e0;
        u16x8 xc = *(const u16x8*)(Xb + rowbase + cb);
        u16x8 xm = {0, 0, 0, 0, 0, 0, 0, 0};
        u16x8 xp = {0, 0, 0, 0, 0, 0, 0, 0};
        if (n > 0)    xm = *(const u16x8*)(Xb + rowbase - 512 + cb);
        if (n < 4095) xp = *(const u16x8*)(Xb + rowbase + 512 + cb);
        float rv[8];
        #pragma unroll
        for (int j = 0; j < 8; ++j) {
            int c = cb + j;
            float lep = b2f(xm[j]) * lw[c * 3] +
                        b2f(xc[j]) * lw[c * 3 + 1] +
                        b2f(xp[j]) * lw[c * 3 + 2] + lb[c];
            rv[j] = o[j] * z + lep;
        }
        float* Of = OUT + rowbase + cb;
        *(float4*)Of       = make_float4(rv[0], rv[1], rv[2], rv[3]);
        *(float4*)(Of + 4) = make_float4(rv[4], rv[5], rv[6], rv[7]);
    }
}

extern "C" void kernel_launch(void* const* d_in, const int* in_sizes, int n_in,
                              void* d_out, int out_size, void* d_ws, size_t ws_size,
                              hipStream_t stream) {
    const float* x   = (const float*)d_in[0];
    const float* Wqk = (const float*)d_in[1];
    const float* bqk = (const float*)d_in[2];
    const float* lw  = (const float*)d_in[3];
    const float* lb  = (const float*)d_in[4];
    float* out = (float*)d_out;

    // workspace (~33.3 MB); kvbuf+ksum contiguous (zeroed by k_prep tail)
    char* w = (char*)d_ws;
    u16* Qb      = (u16*)w;   w += (size_t)16384 * 512 * 2;   // 16 MB
    u16* Xb      = (u16*)w;   w += (size_t)16384 * 512 * 2;   // 16 MB
    u16* WT      = (u16*)w;   w += (size_t)1024 * 512 * 2;    // 1 MB
    float* kvbuf = (float*)w; w += (size_t)64 * 1024 * 4;     // 256 KB
    float* ksum  = (float*)w;                                 // 8 KB (contig)

    k_prep<<<4674, 256, 0, stream>>>(x, Xb, Wqk, WT, kvbuf);
    k_gemm<<<dim3(64, 4), 512, 0, stream>>>(Xb, WT, bqk, Qb, kvbuf, ksum);
    k_out<<<dim3(256, 4), 256, 0, stream>>>(Qb, Xb, kvbuf, ksum, lw, lb, out);
}

// Round 4
// 140.030 us; speedup vs baseline: 2.1480x; 2.1480x over previous
//
#include <hip/hip_runtime.h>

typedef unsigned short u16;
typedef u16   u16x8 __attribute__((ext_vector_type(8)));
typedef short s16x8 __attribute__((ext_vector_type(8)));
typedef float f32x4 __attribute__((ext_vector_type(4)));

__device__ __forceinline__ float b2f(u16 u) {
    return __uint_as_float(((unsigned)u) << 16);
}
__device__ __forceinline__ u16 f2b(float f) {
    unsigned x = __float_as_uint(f);
    x += 0x7fffu + ((x >> 16) & 1u);
    return (u16)(x >> 16);
}
// async global->LDS, 16B per lane; LDS dest = wave-uniform base + lane*16
__device__ __forceinline__ void gload_lds(const u16* g, u16* l) {
    __builtin_amdgcn_global_load_lds(
        (const __attribute__((address_space(1))) unsigned int*)g,
        (__attribute__((address_space(3))) unsigned int*)l, 16, 0, 0);
}

#define THETA_SCALE 0.05190512648261f   // log2(10000)/256

// ---------------- prep: Xb = bf16(x) + WT = bf16(Wqk^T) + zero kvbuf/ksum ---
__global__ __launch_bounds__(256)
void k_prep(const float* __restrict__ X, u16* __restrict__ Xb,
            const float* __restrict__ W, u16* __restrict__ WT,
            float* __restrict__ kvz) {
    if (blockIdx.x < 4096) {
        size_t i = (size_t)(blockIdx.x * 256 + threadIdx.x) * 8;
        float4 a = *(const float4*)(X + i);
        float4 b = *(const float4*)(X + i + 4);
        u16x8 r;
        r[0] = f2b(a.x); r[1] = f2b(a.y); r[2] = f2b(a.z); r[3] = f2b(a.w);
        r[4] = f2b(b.x); r[5] = f2b(b.y); r[6] = f2b(b.z); r[7] = f2b(b.w);
        *(u16x8*)(Xb + i) = r;
    } else if (blockIdx.x < 4608) {
        __shared__ float tile[32][33];
        int bid = blockIdx.x - 4096;        // 0..511 = 32 x 16
        int c0 = (bid & 31) * 32;
        int r0 = (bid >> 5) * 32;
        int tx = threadIdx.x & 31;
        int ty = threadIdx.x >> 5;
        #pragma unroll
        for (int i = 0; i < 4; ++i) {
            int r = ty + i * 8;
            tile[r][tx] = W[(size_t)(r0 + r) * 1024 + c0 + tx];
        }
        __syncthreads();
        #pragma unroll
        for (int i = 0; i < 4; ++i) {
            int r = ty + i * 8;
            WT[(size_t)(c0 + r) * 512 + r0 + tx] = f2b(tile[tx][r]);
        }
    } else {
        // zero kvbuf (65536 f) + ksum (2048 f): 66 blocks x 1024 floats
        size_t i = (size_t)(blockIdx.x - 4608) * 1024 + threadIdx.x * 4;
        *(float4*)(kvz + i) = make_float4(0.f, 0.f, 0.f, 0.f);
    }
}

// ---------------- GEMM: Xb x WT + bias, elu+1 -> Qb (bf16), Kb (bf16) -------
// 256x256 tile, 8 waves (2M x 4N), BK=64 double-buffered, counted vmcnt(8),
// raw s_barrier (no drain), setprio around MFMA clusters.
// XCD-aware block remap: 256 blocks = 8 XCDs x 32; each XCD gets a contiguous
// 8-wide bx chunk x all 4 by, so its working set (2 MB Xb rows + 1 MB WT)
// fits the 4 MB per-XCD L2.
// LDS XOR-swizzle (both sides): LDS chunk kc of row r holds global chunk kc^(r&7)
__global__ __launch_bounds__(512, 2)
void k_gemm(const u16* __restrict__ Xb, const u16* __restrict__ WT,
            const float* __restrict__ bqk,
            u16* __restrict__ Qb, u16* __restrict__ Kb) {
    __shared__ u16 As[2][256 * 64];      // 64 KB
    __shared__ u16 Bs[2][256 * 64];      // 64 KB
    const int t = threadIdx.x;           // 0..511
    // ---- XCD swizzle (dispatch round-robins linear id % 8 across XCDs) ----
    const int lin = blockIdx.x + (blockIdx.y << 6);   // gridDim.x = 64
    const int xcd = lin & 7;
    const int local = lin >> 3;          // 0..31 within XCD
    const int bx = xcd * 8 + (local & 7);
    const int by = local >> 3;           // 0..3
    const int m0 = bx * 256;
    const int n0 = by * 256;
    const int lane = t & 63;
    const int wave = t >> 6;             // 0..7
    const int wm = (wave >> 2) * 128;    // 2 m-wave rows
    const int wn = (wave & 3) * 64;      // 4 n-wave cols
    const int quad = lane >> 4;
    const int l16 = lane & 15;
    const int srow = lane >> 3;          // staging: row within wave's 8-row slice
    const int skc  = lane & 7;           // staging: 16B granule within row

    f32x4 acc[8][4];
    #pragma unroll
    for (int i = 0; i < 8; ++i)
        #pragma unroll
        for (int j = 0; j < 4; ++j) acc[i][j] = (f32x4){0.f, 0.f, 0.f, 0.f};

    // prologue: stage K-tile 0 into buffer 0 (8 gloads/wave)
    #pragma unroll
    for (int c = 0; c < 4; ++c) {
        int row = c * 64 + wave * 8 + srow;
        int kcs = (skc ^ (row & 7)) * 8;
        gload_lds(Xb + (size_t)(m0 + row) * 512 + kcs,
                  &As[0][(c * 64 + wave * 8) * 64]);
        gload_lds(WT + (size_t)(n0 + row) * 512 + kcs,
                  &Bs[0][(c * 64 + wave * 8) * 64]);
    }

    for (int kt = 0; kt < 8; ++kt) {
        const int cur = kt & 1;
        if (kt < 7) {
            const int k0 = (kt + 1) * 64;
            #pragma unroll
            for (int c = 0; c < 4; ++c) {
                int row = c * 64 + wave * 8 + srow;
                int kcs = (skc ^ (row & 7)) * 8;
                gload_lds(Xb + (size_t)(m0 + row) * 512 + k0 + kcs,
                          &As[cur ^ 1][(c * 64 + wave * 8) * 64]);
                gload_lds(WT + (size_t)(n0 + row) * 512 + k0 + kcs,
                          &Bs[cur ^ 1][(c * 64 + wave * 8) * 64]);
            }
            // wait for this tile's 8 loads; next tile's 8 stay in flight
            asm volatile("s_waitcnt vmcnt(8)" ::: "memory");
        } else {
            asm volatile("s_waitcnt vmcnt(0)" ::: "memory");
        }
        __builtin_amdgcn_s_barrier();
        asm volatile("" ::: "memory");

        #pragma unroll
        for (int s = 0; s < 2; ++s) {
            const int cb = s * 4 + quad;
            s16x8 af[8], bf[4];
            #pragma unroll
            for (int f = 0; f < 8; ++f) {
                int row = wm + f * 16 + l16;
                af[f] = *(const s16x8*)&As[cur][row * 64 + ((cb ^ (row & 7)) * 8)];
            }
            #pragma unroll
            for (int j = 0; j < 4; ++j) {
                int row = wn + j * 16 + l16;
                bf[j] = *(const s16x8*)&Bs[cur][row * 64 + ((cb ^ (row & 7)) * 8)];
            }
            __builtin_amdgcn_s_setprio(1);
            #pragma unroll
            for (int f = 0; f < 8; ++f)
                #pragma unroll
                for (int j = 0; j < 4; ++j)
                    acc[f][j] = __builtin_amdgcn_mfma_f32_16x16x32_bf16(
                        af[f], bf[j], acc[f][j], 0, 0, 0);
            __builtin_amdgcn_s_setprio(0);
        }
        asm volatile("" ::: "memory");
        __builtin_amdgcn_s_barrier();
    }

    u16* O = (n0 < 512) ? Qb : Kb;   // block-uniform
    #pragma unroll
    for (int f = 0; f < 8; ++f)
        #pragma unroll
        for (int j = 0; j < 4; ++j) {
            int col = n0 + wn + j * 16 + l16;
            float bias = bqk[col];
            int gc = col & 511;
            #pragma unroll
            for (int r = 0; r < 4; ++r) {
                int grow = m0 + wm + f * 16 + quad * 4 + r;
                float v = acc[f][j][r] + bias;
                v = v > 0.f ? v + 1.f : __expf(v);   // elu(v)+1
                O[(size_t)grow * 512 + gc] = f2b(v);
            }
        }
}

// ---------------- kv via MFMA: kv[d][e] += sum_n kr[n,d]*v[n,e] -------------
// per (bh, chunk): 32x32 GEMM, K=512; channel-major LDS with bank rotation;
// 4 waves = 4 quadrants; atomicAdd into shared kvbuf (proven handoff).
__global__ __launch_bounds__(256)
void k_kv(const u16* __restrict__ Kb, const u16* __restrict__ Xb,
          float* __restrict__ kvbuf, float* __restrict__ ksum) {
    const int bh = blockIdx.x;            // 0..63
    const int b = bh >> 4, h = bh & 15;
    const int nb = blockIdx.y * 512;      // N chunk
    __shared__ u16 krT[32 * 72];          // [c][n], stride 72 (144B, 16B-align)
    __shared__ u16 vT[32 * 72];
    __shared__ float red[64 * 36];        // ksum reduce
    const int t = threadIdx.x;
    const int row = t >> 2;               // 0..63 staging row
    const int c8 = (t & 3) * 8;           // staging channel octet
    const int rot_w = 16 * ((c8 >> 3) & 3);   // bank rotation for writes
    const int lane = t & 63;
    const int wave = t >> 6;
    const int quad = lane >> 4;
    const int l16 = lane & 15;
    const int dq = (wave >> 1) * 16;      // d-quadrant base
    const int eq = (wave & 1) * 16;      // e-quadrant base
    const int ca = dq + l16;              // A channel (d)
    const int cb2 = eq + l16;             // B channel (e)
    const int rot_a = 16 * ((ca >> 3) & 3);
    const int rot_b = 16 * ((cb2 >> 3) & 3);

    float ksl[8] = {0, 0, 0, 0, 0, 0, 0, 0};
    f32x4 acc = {0.f, 0.f, 0.f, 0.f};

    float th[4];
    #pragma unroll
    for (int p = 0; p < 4; ++p)
        th[p] = exp2f(-THETA_SCALE * (float)(h * 16 + (c8 >> 1) + p));

    for (int pass = 0; pass < 8; ++pass) {
        int n = nb + pass * 64 + row;
        size_t base = (size_t)(b * 4096 + n) * 512 + h * 32 + c8;
        u16x8 k8 = *(const u16x8*)(Kb + base);
        u16x8 v8 = *(const u16x8*)(Xb + base);
        float kf[8], kr[8];
        #pragma unroll
        for (int j = 0; j < 8; ++j) kf[j] = b2f(k8[j]);
        #pragma unroll
        for (int p = 0; p < 4; ++p) {
            float sv, cv;
            sincosf((float)n * th[p], &sv, &cv);
            kr[2 * p]     = kf[2 * p] * cv - kf[2 * p + 1] * sv;
            kr[2 * p + 1] = kf[2 * p] * sv + kf[2 * p + 1] * cv;
        }
        #pragma unroll
        for (int j = 0; j < 8; ++j) ksl[j] += kf[j];
        if (pass) __syncthreads();
        int colw = (row + rot_w) & 63;    // rotated column
        #pragma unroll
        for (int j = 0; j < 8; ++j) {
            krT[(c8 + j) * 72 + colw] = f2b(kr[j]);
            vT[(c8 + j) * 72 + colw] = v8[j];
        }
        __syncthreads();
        #pragma unroll
        for (int ks = 0; ks < 64; ks += 32) {
            s16x8 a4 = *(const s16x8*)&krT[ca * 72 + ((ks + quad * 8 + rot_a) & 63)];
            s16x8 b4 = *(const s16x8*)&vT[cb2 * 72 + ((ks + quad * 8 + rot_b) & 63)];
            acc = __builtin_amdgcn_mfma_f32_16x16x32_bf16(a4, b4, acc, 0, 0, 0);
        }
    }

    // kv: D layout col=e=l16, row=d=quad*4+r ; device-scope atomic handoff
    #pragma unroll
    for (int r = 0; r < 4; ++r)
        atomicAdd(&kvbuf[(size_t)bh * 1024 + (dq + quad * 4 + r) * 32 + eq + l16],
                  acc[r]);

    // ksum reduce
    __syncthreads();
    *(float4*)&red[row * 36 + c8]     = make_float4(ksl[0], ksl[1], ksl[2], ksl[3]);
    *(float4*)&red[row * 36 + c8 + 4] = make_float4(ksl[4], ksl[5], ksl[6], ksl[7]);
    __syncthreads();
    if (t < 32) {
        float s = 0.f;
        for (int r = 0; r < 64; ++r) s += red[r * 36 + t];
        atomicAdd(&ksum[bh * 32 + t], s);
    }
}

// ---------------- out = z * (q_rope @ kv)/N + lepe (f32 to d_out) -----------
// phase 2 via MFMA: out[64x32] = qr[64x32] @ kv[32x32]; A = qr_s[row][d] bf16,
// B = kvT_s[e][d] bf16 (same [n][k] B-operand layout as the proven gemm);
// C round-trips LDS so the row-major lepe epilogue stays unchanged.
__global__ __launch_bounds__(256)
void k_out(const u16* __restrict__ Qb, const u16* __restrict__ Xb,
           const float* __restrict__ kvbuf, const float* __restrict__ ksum,
           const float* __restrict__ lw, const float* __restrict__ lb,
           float* __restrict__ OUT) {
    const int b = blockIdx.x >> 6;
    const int nb = (blockIdx.x & 63) * 64;
    const int hbase = blockIdx.y * 4;
    __shared__ u16 kvT_s[32 * 36];     // [e][d] bf16, stride 36
    __shared__ u16 qr_s[64 * 36];      // [row][d] bf16, stride 36
    __shared__ float out_s[64 * 36];   // [row][e] f32, stride 36
    __shared__ float ks_s[32];
    __shared__ float z_s[64];
    const int t = threadIdx.x;
    const int row = t >> 2;          // 0..63 local n
    const int c4 = t & 3;
    const int e0 = c4 * 8;
    const int lane = t & 63;
    const int wave = t >> 6;
    const int quad = lane >> 4;
    const int l16 = lane & 15;
    const float invN = 1.f / 4096.f;
    const int n = nb + row;
    const size_t rowbase = (size_t)(b * 4096 + n) * 512;

    for (int hh = 0; hh < 4; ++hh) {
        const int h = hbase + hh;
        const int bh = b * 16 + h;
        if (hh) __syncthreads();               // prev iteration LDS reads done
        // stage kvT (bf16, transposed) + kmean
        {
            int id = t * 4;                    // 0..1023, e varies fastest
            float4 kvv = *(const float4*)&kvbuf[(size_t)bh * 1024 + id];
            int d = id >> 5, e = id & 31;
            kvT_s[(e + 0) * 36 + d] = f2b(kvv.x * invN);
            kvT_s[(e + 1) * 36 + d] = f2b(kvv.y * invN);
            kvT_s[(e + 2) * 36 + d] = f2b(kvv.z * invN);
            kvT_s[(e + 3) * 36 + d] = f2b(kvv.w * invN);
        }
        if (t < 32) ks_s[t] = ksum[bh * 32 + t] * invN;
        __syncthreads();

        // phase 1: q (bf16), z partial dot, rope, stage qr bf16
        u16x8 q8 = *(const u16x8*)(Qb + rowbase + h * 32 + e0);
        float qf[8];
        #pragma unroll
        for (int j = 0; j < 8; ++j) qf[j] = b2f(q8[j]);
        float part = 0.f;
        #pragma unroll
        for (int j = 0; j < 8; ++j) part += qf[j] * ks_s[e0 + j];
        u16x8 qr8;
        #pragma unroll
        for (int p = 0; p < 4; ++p) {
            float th = exp2f(-THETA_SCALE * (float)(h * 16 + c4 * 4 + p));
            float sv, cv;
            sincosf((float)n * th, &sv, &cv);
            qr8[2 * p]     = f2b(qf[2 * p] * cv - qf[2 * p + 1] * sv);
            qr8[2 * p + 1] = f2b(qf[2 * p] * sv + qf[2 * p + 1] * cv);
        }
        *(u16x8*)&qr_s[row * 36 + e0] = qr8;
        part += __shfl_xor(part, 1);
        part += __shfl_xor(part, 2);
        if (c4 == 0) z_s[row] = 1.f / (part + 1e-6f);
        __syncthreads();

        // phase 2 (MFMA): wave = 16-row tile; 2 e-tiles; K=32 in one step
        {
            f32x4 zero4 = {0.f, 0.f, 0.f, 0.f};
            s16x8 a4 = *(const s16x8*)&qr_s[(wave * 16 + l16) * 36 + quad * 8];
            #pragma unroll
            for (int et = 0; et < 2; ++et) {
                s16x8 b4 = *(const s16x8*)&kvT_s[(et * 16 + l16) * 36 + quad * 8];
                f32x4 cacc = __builtin_amdgcn_mfma_f32_16x16x32_bf16(
                    a4, b4, zero4, 0, 0, 0);
                #pragma unroll
                for (int r = 0; r < 4; ++r)
                    out_s[(wave * 16 + quad * 4 + r) * 36 + et * 16 + l16] = cacc[r];
            }
        }
        __syncthreads();

        // epilogue: read out_s row-major, z scale + lepe + store f32
        const float z = z_s[row];
        float4 o0 = *(const float4*)&out_s[row * 36 + e0];
        float4 o1 = *(const float4*)&out_s[row * 36 + e0 + 4];
        float o[8] = {o0.x, o0.y, o0.z, o0.w, o1.x, o1.y, o1.z, o1.w};
        const int cb = h * 32 + e0;
        u16x8 xc = *(const u16x8*)(Xb + rowbase + cb);
        u16x8 xm = {0, 0, 0, 0, 0, 0, 0, 0};
        u16x8 xp = {0, 0, 0, 0, 0, 0, 0, 0};
        if (n > 0)    xm = *(const u16x8*)(Xb + rowbase - 512 + cb);
        if (n < 4095) xp = *(const u16x8*)(Xb + rowbase + 512 + cb);
        float rv[8];
        #pragma unroll
        for (int j = 0; j < 8; ++j) {
            int c = cb + j;
            float lep = b2f(xm[j]) * lw[c * 3] +
                        b2f(xc[j]) * lw[c * 3 + 1] +
                        b2f(xp[j]) * lw[c * 3 + 2] + lb[c];
            rv[j] = o[j] * z + lep;
        }
        float* Of = OUT + rowbase + cb;
        *(float4*)Of       = make_float4(rv[0], rv[1], rv[2], rv[3]);
        *(float4*)(Of + 4) = make_float4(rv[4], rv[5], rv[6], rv[7]);
    }
}

extern "C" void kernel_launch(void* const* d_in, const int* in_sizes, int n_in,
                              void* d_out, int out_size, void* d_ws, size_t ws_size,
                              hipStream_t stream) {
    const float* x   = (const float*)d_in[0];
    const float* Wqk = (const float*)d_in[1];
    const float* bqk = (const float*)d_in[2];
    const float* lw  = (const float*)d_in[3];
    const float* lb  = (const float*)d_in[4];
    float* out = (float*)d_out;

    // workspace (~49.3 MB); kvbuf+ksum contiguous (zeroed by k_prep tail)
    char* w = (char*)d_ws;
    u16* Kb      = (u16*)w;   w += (size_t)16384 * 512 * 2;   // 16 MB
    u16* Qb      = (u16*)w;   w += (size_t)16384 * 512 * 2;   // 16 MB
    u16* Xb      = (u16*)w;   w += (size_t)16384 * 512 * 2;   // 16 MB
    u16* WT      = (u16*)w;   w += (size_t)1024 * 512 * 2;    // 1 MB
    float* kvbuf = (float*)w; w += (size_t)64 * 1024 * 4;     // 256 KB
    float* ksum  = (float*)w;                                 // 8 KB (contig)

    k_prep<<<4674, 256, 0, stream>>>(x, Xb, Wqk, WT, kvbuf);
    k_gemm<<<dim3(64, 4), 512, 0, stream>>>(Xb, WT, bqk, Qb, Kb);
    k_kv<<<dim3(64, 8), 256, 0, stream>>>(Kb, Xb, kvbuf, ksum);
    k_out<<<dim3(256, 4), 256, 0, stream>>>(Qb, Xb, kvbuf, ksum, lw, lb, out);
}